// Round 9
// baseline (201.782 us; speedup 1.0000x reference)
//
#include <hip/hip_runtime.h>
#include <stdint.h>

typedef short short8 __attribute__((ext_vector_type(8)));
typedef float f32x4 __attribute__((ext_vector_type(4)));

#define TILE 64           // A-tile rows per block (and K_MM reg-tile rows)
#define BCOLS 32          // B-tile cols per m-iteration

__device__ __forceinline__ unsigned short f32_to_bf16(float f) {
    uint32_t u = __builtin_bit_cast(uint32_t, f);
    u += 0x7FFFu + ((u >> 16) & 1u);   // RNE; data has no NaNs
    return (unsigned short)(u >> 16);
}
__device__ __forceinline__ float bf16_to_f32(unsigned short h) {
    return __builtin_bit_cast(float, (uint32_t)h << 16);
}

// async global->LDS DMA, 16 B per lane per issue (global_load_lds_dwordx4).
// HW semantics: per-lane global address; LDS dest = wave-uniform base + lane*16.
typedef const __attribute__((address_space(1))) uint32_t guint;
typedef __attribute__((address_space(3))) uint32_t luint;
__device__ __forceinline__ void dma16(const void* g, void* l) {
    __builtin_amdgcn_global_load_lds((guint*)g, (luint*)l, 16, 0, 0);
}

// Prep: centers fp32 -> bf16 in MFMA fragment layout, cw[m] = {||c||^2 * q, alpha[m]},
// and zero the accumulators (loss, reg, block counter).
// Fragment layout: element (row R, k) -> Bp[(R/16)*2048 + (k/8)*128 + (R%16)*8 + (k%8)]
__global__ void prep_kernel(const float* __restrict__ C,
                            const float* __restrict__ alpha,
                            const float* __restrict__ sigma,
                            unsigned short* __restrict__ Bp,
                            float2* __restrict__ cw,
                            float* __restrict__ acc)
{
    const int t = threadIdx.x;
    const int g = blockIdx.x;          // 16-row group
    const int r = t >> 4;              // row within group
    const int c16 = t & 15;            // 8-elem k-chunk
    const int R = g * 16 + r;

    if (g == 0 && t == 0) {
        acc[0] = 0.f; acc[1] = 0.f;
        ((unsigned int*)acc)[2] = 0u;
    }

    const float4* src = (const float4*)(C + (size_t)R * 128 + c16 * 8);
    float4 va = src[0], vb = src[1];
    unsigned short h[8];
    h[0] = f32_to_bf16(va.x); h[1] = f32_to_bf16(va.y);
    h[2] = f32_to_bf16(va.z); h[3] = f32_to_bf16(va.w);
    h[4] = f32_to_bf16(vb.x); h[5] = f32_to_bf16(vb.y);
    h[6] = f32_to_bf16(vb.z); h[7] = f32_to_bf16(vb.w);
    float ss = 0.f;
    #pragma unroll
    for (int k = 0; k < 8; ++k) {
        float f = bf16_to_f32(h[k]);
        ss = fmaf(f, f, ss);
    }
    uint4 pk;
    pk.x = (uint32_t)h[0] | ((uint32_t)h[1] << 16);
    pk.y = (uint32_t)h[2] | ((uint32_t)h[3] << 16);
    pk.z = (uint32_t)h[4] | ((uint32_t)h[5] << 16);
    pk.w = (uint32_t)h[6] | ((uint32_t)h[7] << 16);
    *reinterpret_cast<uint4*>(Bp + (size_t)g * 2048 + c16 * 128 + r * 8) = pk;

    ss += __shfl_xor(ss, 1);
    ss += __shfl_xor(ss, 2);
    ss += __shfl_xor(ss, 4);
    ss += __shfl_xor(ss, 8);
    if (c16 == 0) {
        float sig = sigma[0];
        float q = 0.7213475204444817f / (sig * sig);  // log2(e)/(2 sigma^2)
        cw[R] = make_float2(ss * q, alpha[R]);
    }
}

// Fused: blocks [0,nA) = preds + loss-sum; blocks [nA,nA+nMt) = K_MM regularizer.
//
// R10 = R9 resubmitted (R9 bench was an infra failure, not a kernel result;
// kernel re-audited: uniform barriers, no OOB, no spin, no masked-exec DMA).
//
// R9/R10: the R2 per-wave loop body VERBATIM (a[8], b[4], one 16-col
// j-group, global cj loads, DMA double-buffer + one __syncthreads/iter --
// every mutation of that body in R3/R4/R5/R6/R8 regressed 104-128us), with
// only the BLOCK ENVELOPE changed: 256 threads = 4 waves (2 row x 2 col
// groups), TILE=64 rows, BCOLS=32. Occupancy arithmetic: at ~68 total regs
// a SIMD fits 7 waves (needs <=73); 4-wave blocks -> 7 blocks/CU = 28
// waves/CU (vs R2's 3x8=24), LDS 17.7KB x 7 = 124 <= 160 OK, grid 1563+32 =
// 1595 <= 7x256 = 1792 slots -> single round, and 7 independent blocks
// de-phase the barrier convoys vs R2's 3. Cost accepted: 2x total DMA (each
// block streams all of Bp: ~24us per-CU L2 traffic, overlapped) and 2x
// barriers at half work each. No forced launch bounds below 128 regs (R1),
// no asm pins (R3), nothing on the MFMA C-chain (R4).
__global__ __launch_bounds__(256, 4)
void fused_kernel(const float* __restrict__ X, int N,
                  const float* __restrict__ Yv,
                  const unsigned short* __restrict__ Bp,
                  const float2* __restrict__ cw,
                  const float* __restrict__ alpha,
                  const float* __restrict__ sigma,
                  const float* __restrict__ penalty,
                  int nA, int nMt, int nBlk,
                  float* __restrict__ preds_out,
                  float* __restrict__ out0,
                  float* __restrict__ acc)   // [0]=loss,[1]=reg,[2]=counter
{
    // ldsB (both 8KB halves, 16KB contiguous) doubles as the A-staging
    // buffer (64 rows x 128 cols bf16 = 16KB) before the m-loop starts.
    __shared__ __align__(16) unsigned short ldsB[2][4096];  // 2 x 8 KB
    __shared__ float a2p[TILE][4];
    __shared__ float predbuf[TILE][2];

    const int t    = threadIdx.x;
    const int lane = t & 63;
    const int wid  = t >> 6;     // 0..3
    const int wr   = wid >> 1;   // 0..1: rows wr*32 .. +32
    const int wc   = wid & 1;    // 0..1: cols wc*16 .. +16 of the 32-col tile
    const int l15  = lane & 15;
    const int quad = lane >> 4;

    const float sig = sigma[0];
    const float q  = 0.7213475204444817f / (sig * sig);
    const float q2 = 2.0f * q;

    const bool regmode = (int)blockIdx.x >= nA;
    int rowbase;
    float rowterm[2][4];
    short8 a[8];   // A fragments, tile-invariant: a[i*4+kk], i in {0,1}

    if (!regmode) {
        rowbase = blockIdx.x * TILE;
        // stage X tile into fragment-layout LDS (whole 16KB of ldsB);
        // each thread converts a quarter-row (32 elems)
        const int r_  = t >> 2;            // 0..63
        const int qtr = t & 3;
        const int grow = rowbase + r_;
        unsigned short* dstbase = &ldsB[0][0] + (r_ >> 4) * 2048 + (r_ & 15) * 8;
        float ss = 0.f;
        if (grow < N) {
            const float4* src = (const float4*)(X + (size_t)grow * 128 + qtr * 32);
            #pragma unroll
            for (int c = 0; c < 4; ++c) {
                float4 va = src[2 * c], vb = src[2 * c + 1];
                unsigned short h0 = f32_to_bf16(va.x), h1 = f32_to_bf16(va.y);
                unsigned short h2 = f32_to_bf16(va.z), h3 = f32_to_bf16(va.w);
                unsigned short h4 = f32_to_bf16(vb.x), h5 = f32_to_bf16(vb.y);
                unsigned short h6 = f32_to_bf16(vb.z), h7 = f32_to_bf16(vb.w);
                float f0 = bf16_to_f32(h0), f1 = bf16_to_f32(h1);
                float f2 = bf16_to_f32(h2), f3 = bf16_to_f32(h3);
                float f4 = bf16_to_f32(h4), f5 = bf16_to_f32(h5);
                float f6 = bf16_to_f32(h6), f7 = bf16_to_f32(h7);
                ss = fmaf(f0, f0, ss); ss = fmaf(f1, f1, ss);
                ss = fmaf(f2, f2, ss); ss = fmaf(f3, f3, ss);
                ss = fmaf(f4, f4, ss); ss = fmaf(f5, f5, ss);
                ss = fmaf(f6, f6, ss); ss = fmaf(f7, f7, ss);
                uint4 pk;
                pk.x = (uint32_t)h0 | ((uint32_t)h1 << 16);
                pk.y = (uint32_t)h2 | ((uint32_t)h3 << 16);
                pk.z = (uint32_t)h4 | ((uint32_t)h5 << 16);
                pk.w = (uint32_t)h6 | ((uint32_t)h7 << 16);
                *reinterpret_cast<uint4*>(dstbase + (qtr * 4 + c) * 128) = pk;
            }
        } else {
            uint4 z; z.x = z.y = z.z = z.w = 0u;
            #pragma unroll
            for (int c = 0; c < 4; ++c)
                *reinterpret_cast<uint4*>(dstbase + (qtr * 4 + c) * 128) = z;
        }
        a2p[r_][qtr] = ss;
        __syncthreads();
        #pragma unroll
        for (int i = 0; i < 2; ++i)
            #pragma unroll
            for (int r = 0; r < 4; ++r) {
                int rl = wr * 32 + i * 16 + quad * 4 + r;
                rowterm[i][r] = (a2p[rl][0] + a2p[rl][1] + a2p[rl][2] + a2p[rl][3]) * q;
            }
        // hoist A fragments: 8 ds_read_b128, once for the whole kernel
        const unsigned short* aLds = &ldsB[0][0] + (size_t)(wr * 2) * 2048 + lane * 8;
        #pragma unroll
        for (int i = 0; i < 2; ++i)
            #pragma unroll
            for (int kk = 0; kk < 4; ++kk)
                a[i * 4 + kk] = *reinterpret_cast<const short8*>(aLds + (size_t)i * 2048 + kk * 512);
        __syncthreads();   // all waves done reading A from ldsB before DMA overwrites
    } else {
        const int b2 = (int)blockIdx.x - nA;
        rowbase = b2 * TILE;
        // 64 rows = 4 row-groups of 16: groups b2*4 .. b2*4+3
        const unsigned short* aG = Bp + (size_t)(b2 * 4 + wr * 2) * 2048 + lane * 8;
        #pragma unroll
        for (int i = 0; i < 2; ++i)
            #pragma unroll
            for (int kk = 0; kk < 4; ++kk)
                a[i * 4 + kk] = *reinterpret_cast<const short8*>(aG + (size_t)i * 2048 + kk * 512);
        #pragma unroll
        for (int i = 0; i < 2; ++i)
            #pragma unroll
            for (int r = 0; r < 4; ++r)
                rowterm[i][r] = cw[rowbase + wr * 32 + i * 16 + quad * 4 + r].x;
    }

    float srow[2][4] = {};
    const float2* cwb = cw + wc * 16 + l15;

    // this wave stages its 2 KB quarter of each 8KB tile: 2 x 1KB DMA issues
    const int ldq = wid * 1024 + lane * 8;   // element offset (shorts)

    // DMA tile 0 into ldsB[0]
    {
        const unsigned short* g = Bp + ldq;
        unsigned short* l = &ldsB[0][0] + ldq;
        #pragma unroll
        for (int k = 0; k < 2; ++k)
            dma16(g + k * 512, l + k * 512);
    }
    __syncthreads();   // vmcnt drain: tile 0 resident

    for (int mt = 0; mt < nMt; ++mt) {
        if (mt + 1 < nMt) {
            // fire-and-forget DMA of tile mt+1 into the other buffer;
            // drained by the barrier at the END of this iteration.
            const unsigned short* g = Bp + (size_t)(mt + 1) * 4096 + ldq;
            unsigned short* l = &ldsB[(mt + 1) & 1][0] + ldq;
            #pragma unroll
            for (int k = 0; k < 2; ++k)
                dma16(g + k * 512, l + k * 512);
        }

        // column constants for this tile (L2-hot; latency covered by TLP)
        float2 cj = cwb[(size_t)mt * 32];

        // compute tile mt from LDS: this wave's 16-col group, K=128
        const unsigned short* bfr = &ldsB[mt & 1][0] + (size_t)wc * 2048 + lane * 8;
        {
            short8 b[4];
            #pragma unroll
            for (int kk = 0; kk < 4; ++kk)
                b[kk] = *reinterpret_cast<const short8*>(bfr + kk * 512);

            f32x4 acc4[2];
            #pragma unroll
            for (int i = 0; i < 2; ++i) acc4[i] = (f32x4){0.f, 0.f, 0.f, 0.f};
            #pragma unroll
            for (int kk = 0; kk < 4; ++kk)
                #pragma unroll
                for (int i = 0; i < 2; ++i)
                    acc4[i] = __builtin_amdgcn_mfma_f32_16x16x32_bf16(
                        a[i * 4 + kk], b[kk], acc4[i], 0, 0, 0);

            // epilogue: u = 2q*dot - (q*x2 + q*c2) <= ~0 ; srow += exp2(u)*alpha
            #pragma unroll
            for (int i = 0; i < 2; ++i) {
                #pragma unroll
                for (int r = 0; r < 4; ++r) {
                    float u = fmaf(acc4[i][r], q2, -(rowterm[i][r] + cj.x));
                    float e = __builtin_amdgcn_exp2f(u);
                    srow[i][r] = fmaf(e, cj.y, srow[i][r]);
                }
            }
        }

        __syncthreads();   // drains DMA(mt+1); all waves done reading buf[mt&1]
    }

    // reduce srow over the 16 lanes sharing a row
    #pragma unroll
    for (int i = 0; i < 2; ++i) {
        #pragma unroll
        for (int r = 0; r < 4; ++r) {
            int rl = wr * 32 + i * 16 + quad * 4 + r;
            float v = srow[i][r];
            v += __shfl_xor(v, 1);
            v += __shfl_xor(v, 2);
            v += __shfl_xor(v, 4);
            v += __shfl_xor(v, 8);
            if (l15 == 0)
                predbuf[rl][wc] = v;
        }
    }
    __syncthreads();

    float contrib = 0.f;
    if (t < TILE) {
        int grow = rowbase + t;
        if (!regmode) {
            if (grow < N) {
                float pred = predbuf[t][0] + predbuf[t][1];
                preds_out[grow] = pred;
                float d = pred - Yv[grow];
                contrib = d * d;
            }
        } else {
            float pred = predbuf[t][0] + predbuf[t][1];
            contrib = alpha[grow] * pred;
        }
    }
    contrib += __shfl_xor(contrib, 1);
    contrib += __shfl_xor(contrib, 2);
    contrib += __shfl_xor(contrib, 4);
    contrib += __shfl_xor(contrib, 8);
    contrib += __shfl_xor(contrib, 16);
    contrib += __shfl_xor(contrib, 32);
    if (lane == 0 && wid == 0) atomicAdd(regmode ? (acc + 1) : (acc + 0), contrib);

    __syncthreads();   // all waves' atomics drained before counting
    if (t == 0) {
        __threadfence();
        unsigned int old = atomicAdd((unsigned int*)(acc + 2), 1u);
        if (old == (unsigned int)(nBlk - 1)) {
            float lv = atomicAdd(acc + 0, 0.0f);   // coherent read-back
            float rv = atomicAdd(acc + 1, 0.0f);
            out0[0] = lv / (float)N + __expf(-penalty[0]) * rv;
        }
    }
}

extern "C" void kernel_launch(void* const* d_in, const int* in_sizes, int n_in,
                              void* d_out, int out_size, void* d_ws, size_t ws_size,
                              hipStream_t stream) {
    const float* X       = (const float*)d_in[0];
    const float* Y       = (const float*)d_in[1];
    const float* centers = (const float*)d_in[2];
    const float* alpha   = (const float*)d_in[3];
    const float* sigma   = (const float*)d_in[4];
    const float* penalty = (const float*)d_in[5];
    float* out = (float*)d_out;

    const int N = in_sizes[1];   // Y is [N,1]
    const int M = in_sizes[3];   // alpha is [M,1]

    unsigned short* Bp = (unsigned short*)d_ws;                 // M*128 bf16 = M*256 B
    float2* cw = (float2*)((char*)d_ws + (size_t)M * 256);      // M*8 B
    float* acc = (float*)((char*)d_ws + (size_t)M * 264);       // loss, reg, counter

    prep_kernel<<<M / 16, 256, 0, stream>>>(centers, alpha, sigma, Bp, cw, acc);

    const int nA  = (N + TILE - 1) / TILE;
    const int nMt = M / BCOLS;            // 32-col B tiles
    const int nBlk = nA + M / TILE;
    fused_kernel<<<nBlk, 256, 0, stream>>>(X, N, Y, Bp, cw, alpha, sigma, penalty,
                                           nA, nMt, nBlk, out + 1, out, acc);
}

// Round 10
// 185.392 us; speedup vs baseline: 1.0884x; 1.0884x over previous
//
#include <hip/hip_runtime.h>
#include <stdint.h>

typedef short short8 __attribute__((ext_vector_type(8)));
typedef float f32x4 __attribute__((ext_vector_type(4)));

#define TILE 128          // A-tile rows per block (and K_MM reg-tile rows)
#define BCOLS 64          // B-tile cols per m-iteration

__device__ __forceinline__ unsigned short f32_to_bf16(float f) {
    uint32_t u = __builtin_bit_cast(uint32_t, f);
    u += 0x7FFFu + ((u >> 16) & 1u);   // RNE; data has no NaNs
    return (unsigned short)(u >> 16);
}
__device__ __forceinline__ float bf16_to_f32(unsigned short h) {
    return __builtin_bit_cast(float, (uint32_t)h << 16);
}

// async global->LDS DMA, 16 B per lane per issue (global_load_lds_dwordx4).
// HW semantics: per-lane global address; LDS dest = wave-uniform base + lane*16.
typedef const __attribute__((address_space(1))) uint32_t guint;
typedef __attribute__((address_space(3))) uint32_t luint;
__device__ __forceinline__ void dma16(const void* g, void* l) {
    __builtin_amdgcn_global_load_lds((guint*)g, (luint*)l, 16, 0, 0);
}

// Prep: centers fp32 -> bf16 in MFMA fragment layout, cw[m] = {||c||^2 * q, alpha[m]},
// and zero the accumulators (loss, reg, block counter).
// Fragment layout: element (row R, k) -> Bp[(R/16)*2048 + (k/8)*128 + (R%16)*8 + (k%8)]
__global__ void prep_kernel(const float* __restrict__ C,
                            const float* __restrict__ alpha,
                            const float* __restrict__ sigma,
                            unsigned short* __restrict__ Bp,
                            float2* __restrict__ cw,
                            float* __restrict__ acc)
{
    const int t = threadIdx.x;
    const int g = blockIdx.x;          // 16-row group
    const int r = t >> 4;              // row within group
    const int c16 = t & 15;            // 8-elem k-chunk
    const int R = g * 16 + r;

    if (g == 0 && t == 0) {
        acc[0] = 0.f; acc[1] = 0.f;
        ((unsigned int*)acc)[2] = 0u;
    }

    const float4* src = (const float4*)(C + (size_t)R * 128 + c16 * 8);
    float4 va = src[0], vb = src[1];
    unsigned short h[8];
    h[0] = f32_to_bf16(va.x); h[1] = f32_to_bf16(va.y);
    h[2] = f32_to_bf16(va.z); h[3] = f32_to_bf16(va.w);
    h[4] = f32_to_bf16(vb.x); h[5] = f32_to_bf16(vb.y);
    h[6] = f32_to_bf16(vb.z); h[7] = f32_to_bf16(vb.w);
    float ss = 0.f;
    #pragma unroll
    for (int k = 0; k < 8; ++k) {
        float f = bf16_to_f32(h[k]);
        ss = fmaf(f, f, ss);
    }
    uint4 pk;
    pk.x = (uint32_t)h[0] | ((uint32_t)h[1] << 16);
    pk.y = (uint32_t)h[2] | ((uint32_t)h[3] << 16);
    pk.z = (uint32_t)h[4] | ((uint32_t)h[5] << 16);
    pk.w = (uint32_t)h[6] | ((uint32_t)h[7] << 16);
    *reinterpret_cast<uint4*>(Bp + (size_t)g * 2048 + c16 * 128 + r * 8) = pk;

    ss += __shfl_xor(ss, 1);
    ss += __shfl_xor(ss, 2);
    ss += __shfl_xor(ss, 4);
    ss += __shfl_xor(ss, 8);
    if (c16 == 0) {
        float sig = sigma[0];
        float q = 0.7213475204444817f / (sig * sig);  // log2(e)/(2 sigma^2)
        cw[R] = make_float2(ss * q, alpha[R]);
    }
}

// Fused: blocks [0,nA) = preds + loss-sum; blocks [nA,nA+nMt) = K_MM regularizer.
// 512 threads = 8 waves in a 4(row)x2(col) grid; each wave owns 32 rows x 32
// cols of the 128x64 tile.
//
// R11 = R2 RESTORED VERBATIM -- the empirically optimal configuration.
// Eight structural experiments, all regressions vs R2's 76us fused:
//   R3  counted vmcnt + sched_barrier pins          -> 128us (descheduled)
//   R4  rowterm via LDS on the MFMA C-chain         -> 104us
//   R5  barrier-free, B from global (L2)            -> 124us (no SWP by hipcc)
//   R6  manual register double-buffer               -> 121us (compiler re-sank)
//   R7  8x1 wave geometry (2x LDS amplification)    -> 113us
//   R8  cj DMA'd to LDS (+masked-exec DMA)          -> 116us
//   R10 4-wave blocks, TILE=64/BCOLS=32             -> 124us (fixed per-iter cost)
// Conclusions baked in: (1) hipcc neither preserves manual pipelining nor
// generates its own for global loads; the DMA-dbuf + one __syncthreads/iter
// loop is the unique fast schedule. (2) Per-iteration latency has a large
// fixed component -- fewer, bigger iterations win. (3) Any source-level
// change to the m-loop body perturbs the scheduler (VGPR count drops below
// ~60 = descheduled signature). Wall model: wall = per-block-work/(blocks/CU),
// R2 runs 3 blocks/CU (68 total regs -> 7 waves/SIMD).
__global__ __launch_bounds__(512, 4)
void fused_kernel(const float* __restrict__ X, int N,
                  const float* __restrict__ Yv,
                  const unsigned short* __restrict__ Bp,
                  const float2* __restrict__ cw,
                  const float* __restrict__ alpha,
                  const float* __restrict__ sigma,
                  const float* __restrict__ penalty,
                  int nA, int nMt, int nBlk,
                  float* __restrict__ preds_out,
                  float* __restrict__ out0,
                  float* __restrict__ acc)   // [0]=loss,[1]=reg,[2]=counter
{
    // ldsB[0] doubles as the A-staging buffer before the m-loop starts.
    __shared__ __align__(16) unsigned short ldsB[2][8192];  // 2 x 16 KB
    __shared__ float a2p[TILE][4];
    __shared__ float predbuf[TILE][2];

    const int t    = threadIdx.x;
    const int lane = t & 63;
    const int wid  = t >> 6;     // 0..7
    const int wr   = wid >> 1;   // 0..3: rows wr*32 .. +32
    const int wc   = wid & 1;    // 0..1: cols wc*32 .. +32
    const int l15  = lane & 15;
    const int quad = lane >> 4;

    const float sig = sigma[0];
    const float q  = 0.7213475204444817f / (sig * sig);
    const float q2 = 2.0f * q;

    const bool regmode = (int)blockIdx.x >= nA;
    int rowbase;
    float rowterm[2][4];
    short8 a[8];   // A fragments, tile-invariant: a[i*4+kk], i in {0,1}

    if (!regmode) {
        rowbase = blockIdx.x * TILE;
        // stage X tile into fragment-layout LDS; each thread converts a
        // quarter-row (32 elems)
        const int r_  = t >> 2;
        const int qtr = t & 3;
        const int grow = rowbase + r_;
        unsigned short* dstbase = &ldsB[0][0] + (r_ >> 4) * 2048 + (r_ & 15) * 8;
        float ss = 0.f;
        if (grow < N) {
            const float4* src = (const float4*)(X + (size_t)grow * 128 + qtr * 32);
            #pragma unroll
            for (int c = 0; c < 4; ++c) {
                float4 va = src[2 * c], vb = src[2 * c + 1];
                unsigned short h0 = f32_to_bf16(va.x), h1 = f32_to_bf16(va.y);
                unsigned short h2 = f32_to_bf16(va.z), h3 = f32_to_bf16(va.w);
                unsigned short h4 = f32_to_bf16(vb.x), h5 = f32_to_bf16(vb.y);
                unsigned short h6 = f32_to_bf16(vb.z), h7 = f32_to_bf16(vb.w);
                float f0 = bf16_to_f32(h0), f1 = bf16_to_f32(h1);
                float f2 = bf16_to_f32(h2), f3 = bf16_to_f32(h3);
                float f4 = bf16_to_f32(h4), f5 = bf16_to_f32(h5);
                float f6 = bf16_to_f32(h6), f7 = bf16_to_f32(h7);
                ss = fmaf(f0, f0, ss); ss = fmaf(f1, f1, ss);
                ss = fmaf(f2, f2, ss); ss = fmaf(f3, f3, ss);
                ss = fmaf(f4, f4, ss); ss = fmaf(f5, f5, ss);
                ss = fmaf(f6, f6, ss); ss = fmaf(f7, f7, ss);
                uint4 pk;
                pk.x = (uint32_t)h0 | ((uint32_t)h1 << 16);
                pk.y = (uint32_t)h2 | ((uint32_t)h3 << 16);
                pk.z = (uint32_t)h4 | ((uint32_t)h5 << 16);
                pk.w = (uint32_t)h6 | ((uint32_t)h7 << 16);
                *reinterpret_cast<uint4*>(dstbase + (qtr * 4 + c) * 128) = pk;
            }
        } else {
            uint4 z; z.x = z.y = z.z = z.w = 0u;
            #pragma unroll
            for (int c = 0; c < 4; ++c)
                *reinterpret_cast<uint4*>(dstbase + (qtr * 4 + c) * 128) = z;
        }
        a2p[r_][qtr] = ss;
        __syncthreads();
        #pragma unroll
        for (int i = 0; i < 2; ++i)
            #pragma unroll
            for (int r = 0; r < 4; ++r) {
                int rl = wr * 32 + i * 16 + quad * 4 + r;
                rowterm[i][r] = (a2p[rl][0] + a2p[rl][1] + a2p[rl][2] + a2p[rl][3]) * q;
            }
        // hoist A fragments: 8 ds_read_b128, once for the whole kernel
        const unsigned short* aLds = &ldsB[0][0] + (size_t)(wr * 2) * 2048 + lane * 8;
        #pragma unroll
        for (int i = 0; i < 2; ++i)
            #pragma unroll
            for (int kk = 0; kk < 4; ++kk)
                a[i * 4 + kk] = *reinterpret_cast<const short8*>(aLds + (size_t)i * 2048 + kk * 512);
        __syncthreads();   // all waves done reading A from ldsB[0] before DMA overwrites
    } else {
        const int b2 = (int)blockIdx.x - nA;
        rowbase = b2 * TILE;
        const unsigned short* aG = Bp + (size_t)(b2 * 8 + wr * 2) * 2048 + lane * 8;
        #pragma unroll
        for (int i = 0; i < 2; ++i)
            #pragma unroll
            for (int kk = 0; kk < 4; ++kk)
                a[i * 4 + kk] = *reinterpret_cast<const short8*>(aG + (size_t)i * 2048 + kk * 512);
        #pragma unroll
        for (int i = 0; i < 2; ++i)
            #pragma unroll
            for (int r = 0; r < 4; ++r)
                rowterm[i][r] = cw[rowbase + wr * 32 + i * 16 + quad * 4 + r].x;
    }

    float srow[2][4] = {};
    const float2* cwb = cw + wc * 32 + l15;

    // this wave stages its 2 KB eighth of each 16KB tile: 2 x 1KB DMA issues
    const int ldq = wid * 1024 + lane * 8;   // element offset (shorts)

    // DMA tile 0 into ldsB[0]
    {
        const unsigned short* g = Bp + ldq;
        unsigned short* l = &ldsB[0][0] + ldq;
        #pragma unroll
        for (int k = 0; k < 2; ++k)
            dma16(g + k * 512, l + k * 512);
    }
    __syncthreads();   // vmcnt drain: tile 0 resident

    for (int mt = 0; mt < nMt; ++mt) {
        if (mt + 1 < nMt) {
            // fire-and-forget DMA of tile mt+1 into the other buffer;
            // drained by the barrier at the END of this iteration.
            const unsigned short* g = Bp + (size_t)(mt + 1) * 8192 + ldq;
            unsigned short* l = &ldsB[(mt + 1) & 1][0] + ldq;
            #pragma unroll
            for (int k = 0; k < 2; ++k)
                dma16(g + k * 512, l + k * 512);
        }

        // column constants for this tile (L2-hot; latency covered by TLP)
        float2 cj[2];
        #pragma unroll
        for (int j = 0; j < 2; ++j) cj[j] = cwb[(size_t)mt * 64 + j * 16];

        // compute tile mt from LDS: 2 column groups of 16, K=128 each
        const unsigned short* bfr = &ldsB[mt & 1][0] + (size_t)(wc * 2) * 2048 + lane * 8;
        #pragma unroll
        for (int j = 0; j < 2; ++j) {
            short8 b[4];
            #pragma unroll
            for (int kk = 0; kk < 4; ++kk)
                b[kk] = *reinterpret_cast<const short8*>(bfr + (size_t)j * 2048 + kk * 512);

            f32x4 acc4[2];
            #pragma unroll
            for (int i = 0; i < 2; ++i) acc4[i] = (f32x4){0.f, 0.f, 0.f, 0.f};
            #pragma unroll
            for (int kk = 0; kk < 4; ++kk)
                #pragma unroll
                for (int i = 0; i < 2; ++i)
                    acc4[i] = __builtin_amdgcn_mfma_f32_16x16x32_bf16(
                        a[i * 4 + kk], b[kk], acc4[i], 0, 0, 0);

            // epilogue: u = 2q*dot - (q*x2 + q*c2) <= ~0 ; srow += exp2(u)*alpha
            #pragma unroll
            for (int i = 0; i < 2; ++i) {
                #pragma unroll
                for (int r = 0; r < 4; ++r) {
                    float u = fmaf(acc4[i][r], q2, -(rowterm[i][r] + cj[j].x));
                    float e = __builtin_amdgcn_exp2f(u);
                    srow[i][r] = fmaf(e, cj[j].y, srow[i][r]);
                }
            }
        }

        __syncthreads();   // drains DMA(mt+1); all waves done reading buf[mt&1]
    }

    // reduce srow over the 16 lanes sharing a row
    #pragma unroll
    for (int i = 0; i < 2; ++i) {
        #pragma unroll
        for (int r = 0; r < 4; ++r) {
            int rl = wr * 32 + i * 16 + quad * 4 + r;
            float v = srow[i][r];
            v += __shfl_xor(v, 1);
            v += __shfl_xor(v, 2);
            v += __shfl_xor(v, 4);
            v += __shfl_xor(v, 8);
            if (l15 == 0)
                predbuf[rl][wc] = v;
        }
    }
    __syncthreads();

    float contrib = 0.f;
    if (t < TILE) {
        int grow = rowbase + t;
        if (!regmode) {
            if (grow < N) {
                float pred = predbuf[t][0] + predbuf[t][1];
                preds_out[grow] = pred;
                float d = pred - Yv[grow];
                contrib = d * d;
            }
        } else {
            float pred = predbuf[t][0] + predbuf[t][1];
            contrib = alpha[grow] * pred;
        }
    }
    contrib += __shfl_xor(contrib, 1);
    contrib += __shfl_xor(contrib, 2);
    contrib += __shfl_xor(contrib, 4);
    contrib += __shfl_xor(contrib, 8);
    contrib += __shfl_xor(contrib, 16);
    contrib += __shfl_xor(contrib, 32);
    if (lane == 0 && wid < 2) atomicAdd(regmode ? (acc + 1) : (acc + 0), contrib);

    __syncthreads();   // all waves' atomics drained before counting
    if (t == 0) {
        __threadfence();
        unsigned int old = atomicAdd((unsigned int*)(acc + 2), 1u);
        if (old == (unsigned int)(nBlk - 1)) {
            float lv = atomicAdd(acc + 0, 0.0f);   // coherent read-back
            float rv = atomicAdd(acc + 1, 0.0f);
            out0[0] = lv / (float)N + __expf(-penalty[0]) * rv;
        }
    }
}

extern "C" void kernel_launch(void* const* d_in, const int* in_sizes, int n_in,
                              void* d_out, int out_size, void* d_ws, size_t ws_size,
                              hipStream_t stream) {
    const float* X       = (const float*)d_in[0];
    const float* Y       = (const float*)d_in[1];
    const float* centers = (const float*)d_in[2];
    const float* alpha   = (const float*)d_in[3];
    const float* sigma   = (const float*)d_in[4];
    const float* penalty = (const float*)d_in[5];
    float* out = (float*)d_out;

    const int N = in_sizes[1];   // Y is [N,1]
    const int M = in_sizes[3];   // alpha is [M,1]

    unsigned short* Bp = (unsigned short*)d_ws;                 // M*128 bf16 = M*256 B
    float2* cw = (float2*)((char*)d_ws + (size_t)M * 256);      // M*8 B
    float* acc = (float*)((char*)d_ws + (size_t)M * 264);       // loss, reg, counter

    prep_kernel<<<M / 16, 256, 0, stream>>>(centers, alpha, sigma, Bp, cw, acc);

    const int nA  = (N + TILE - 1) / TILE;
    const int nMt = M / BCOLS;            // 64-col B tiles
    const int nBlk = nA + M / TILE;
    fused_kernel<<<nBlk, 512, 0, stream>>>(X, N, Y, Bp, cw, alpha, sigma, penalty,
                                           nA, nMt, nBlk, out + 1, out, acc);
}

// Round 11
// 177.405 us; speedup vs baseline: 1.1374x; 1.0450x over previous
//
#include <hip/hip_runtime.h>
#include <stdint.h>

typedef short short8 __attribute__((ext_vector_type(8)));
typedef float f32x4 __attribute__((ext_vector_type(4)));

#define TILE 128          // A-tile rows per block (and K_MM reg-tile rows)
#define BCOLS 64          // B-tile cols per m-iteration

__device__ __forceinline__ unsigned short f32_to_bf16(float f) {
    uint32_t u = __builtin_bit_cast(uint32_t, f);
    u += 0x7FFFu + ((u >> 16) & 1u);   // RNE; data has no NaNs
    return (unsigned short)(u >> 16);
}
__device__ __forceinline__ float bf16_to_f32(unsigned short h) {
    return __builtin_bit_cast(float, (uint32_t)h << 16);
}

// async global->LDS DMA, 16 B per lane per issue (global_load_lds_dwordx4).
// HW semantics: per-lane global address; LDS dest = wave-uniform base + lane*16.
typedef const __attribute__((address_space(1))) uint32_t guint;
typedef __attribute__((address_space(3))) uint32_t luint;
__device__ __forceinline__ void dma16(const void* g, void* l) {
    __builtin_amdgcn_global_load_lds((guint*)g, (luint*)l, 16, 0, 0);
}

// Prep: centers fp32 -> bf16 in MFMA fragment layout, cw[m] = {||c||^2 * q, alpha[m]},
// and zero the accumulators (loss, reg, block counter).
// Fragment layout: element (row R, k) -> Bp[(R/16)*2048 + (k/8)*128 + (R%16)*8 + (k%8)]
__global__ void prep_kernel(const float* __restrict__ C,
                            const float* __restrict__ alpha,
                            const float* __restrict__ sigma,
                            unsigned short* __restrict__ Bp,
                            float2* __restrict__ cw,
                            float* __restrict__ acc)
{
    const int t = threadIdx.x;
    const int g = blockIdx.x;          // 16-row group
    const int r = t >> 4;              // row within group
    const int c16 = t & 15;            // 8-elem k-chunk
    const int R = g * 16 + r;

    if (g == 0 && t == 0) {
        acc[0] = 0.f; acc[1] = 0.f;
        ((unsigned int*)acc)[2] = 0u;
    }

    const float4* src = (const float4*)(C + (size_t)R * 128 + c16 * 8);
    float4 va = src[0], vb = src[1];
    unsigned short h[8];
    h[0] = f32_to_bf16(va.x); h[1] = f32_to_bf16(va.y);
    h[2] = f32_to_bf16(va.z); h[3] = f32_to_bf16(va.w);
    h[4] = f32_to_bf16(vb.x); h[5] = f32_to_bf16(vb.y);
    h[6] = f32_to_bf16(vb.z); h[7] = f32_to_bf16(vb.w);
    float ss = 0.f;
    #pragma unroll
    for (int k = 0; k < 8; ++k) {
        float f = bf16_to_f32(h[k]);
        ss = fmaf(f, f, ss);
    }
    uint4 pk;
    pk.x = (uint32_t)h[0] | ((uint32_t)h[1] << 16);
    pk.y = (uint32_t)h[2] | ((uint32_t)h[3] << 16);
    pk.z = (uint32_t)h[4] | ((uint32_t)h[5] << 16);
    pk.w = (uint32_t)h[6] | ((uint32_t)h[7] << 16);
    *reinterpret_cast<uint4*>(Bp + (size_t)g * 2048 + c16 * 128 + r * 8) = pk;

    ss += __shfl_xor(ss, 1);
    ss += __shfl_xor(ss, 2);
    ss += __shfl_xor(ss, 4);
    ss += __shfl_xor(ss, 8);
    if (c16 == 0) {
        float sig = sigma[0];
        float q = 0.7213475204444817f / (sig * sig);  // log2(e)/(2 sigma^2)
        cw[R] = make_float2(ss * q, alpha[R]);
    }
}

// Fused: blocks [0,nA) = preds + loss-sum; blocks [nA,nA+nMt) = K_MM regularizer.
// 512 threads = 8 waves in a 4(row)x2(col) grid; each wave owns 32 rows x 32
// cols of the 128x64 tile. Structure: double-buffered 16KB DMA tiles, one
// __syncthreads per iteration, compiler-scheduled loop body.
//
// R12 = the Round-4 variant restored, now known-best on the CURRENT
// toolchain. Session discovery (R11): containers changed compilers
// mid-session -- identical source that measured 76us fused (VGPR 60/SGPR 64)
// now compiles to VGPR 48/SGPR 48 and runs 112us. Re-ranking only the
// SGPR-48-cohort measurements: this rtl-C-init variant = 104us fused (best),
// plain R2 source = 112, 8x1 geometry = 113, cj-in-LDS = 116, others 121-128.
//
// The variant: rowterm[2][4] (8 regs) is eliminated by folding the row term
// into the MFMA C-operand. rtl[row] = -||x_row||^2/2 in LDS (exact:
// rowterm/q2 = ss/2, power-of-2 divide); each j-group inits acc4 via a
// broadcast ds_read of rtl, so u = fmaf(acc, q2, -cj.x) and the per-output
// rowterm+cj.x add disappears (epilogue 4 -> 3 VALU/output). On the current
// compiler this raises occupancy 29 -> 41% and wins ~8%.
__global__ __launch_bounds__(512, 4)
void fused_kernel(const float* __restrict__ X, int N,
                  const float* __restrict__ Yv,
                  const unsigned short* __restrict__ Bp,
                  const float2* __restrict__ cw,
                  const float* __restrict__ alpha,
                  const float* __restrict__ sigma,
                  const float* __restrict__ penalty,
                  int nA, int nMt, int nBlk,
                  float* __restrict__ preds_out,
                  float* __restrict__ out0,
                  float* __restrict__ acc)   // [0]=loss,[1]=reg,[2]=counter
{
    // ldsB[0] doubles as the A-staging buffer before the m-loop starts.
    __shared__ __align__(16) unsigned short ldsB[2][8192];  // 2 x 16 KB
    __shared__ float a2p[TILE][4];
    __shared__ float predbuf[TILE][2];
    __shared__ __align__(16) float rtl[TILE];   // -||row||^2 / 2 (acc C-init)

    const int t    = threadIdx.x;
    const int lane = t & 63;
    const int wid  = t >> 6;     // 0..7
    const int wr   = wid >> 1;   // 0..3: rows wr*32 .. +32
    const int wc   = wid & 1;    // 0..1: cols wc*32 .. +32
    const int l15  = lane & 15;
    const int quad = lane >> 4;

    const float sig = sigma[0];
    const float q  = 0.7213475204444817f / (sig * sig);
    const float q2 = 2.0f * q;

    const bool regmode = (int)blockIdx.x >= nA;
    int rowbase;
    short8 a[8];   // A fragments, tile-invariant: a[i*4+kk], i in {0,1}

    if (!regmode) {
        rowbase = blockIdx.x * TILE;
        // stage X tile into fragment-layout LDS (whole 32KB of ldsB);
        // each thread converts a quarter-row (32 elems)
        const int r_  = t >> 2;
        const int qtr = t & 3;
        const int grow = rowbase + r_;
        unsigned short* dstbase = &ldsB[0][0] + (r_ >> 4) * 2048 + (r_ & 15) * 8;
        float ss = 0.f;
        if (grow < N) {
            const float4* src = (const float4*)(X + (size_t)grow * 128 + qtr * 32);
            #pragma unroll
            for (int c = 0; c < 4; ++c) {
                float4 va = src[2 * c], vb = src[2 * c + 1];
                unsigned short h0 = f32_to_bf16(va.x), h1 = f32_to_bf16(va.y);
                unsigned short h2 = f32_to_bf16(va.z), h3 = f32_to_bf16(va.w);
                unsigned short h4 = f32_to_bf16(vb.x), h5 = f32_to_bf16(vb.y);
                unsigned short h6 = f32_to_bf16(vb.z), h7 = f32_to_bf16(vb.w);
                float f0 = bf16_to_f32(h0), f1 = bf16_to_f32(h1);
                float f2 = bf16_to_f32(h2), f3 = bf16_to_f32(h3);
                float f4 = bf16_to_f32(h4), f5 = bf16_to_f32(h5);
                float f6 = bf16_to_f32(h6), f7 = bf16_to_f32(h7);
                ss = fmaf(f0, f0, ss); ss = fmaf(f1, f1, ss);
                ss = fmaf(f2, f2, ss); ss = fmaf(f3, f3, ss);
                ss = fmaf(f4, f4, ss); ss = fmaf(f5, f5, ss);
                ss = fmaf(f6, f6, ss); ss = fmaf(f7, f7, ss);
                uint4 pk;
                pk.x = (uint32_t)h0 | ((uint32_t)h1 << 16);
                pk.y = (uint32_t)h2 | ((uint32_t)h3 << 16);
                pk.z = (uint32_t)h4 | ((uint32_t)h5 << 16);
                pk.w = (uint32_t)h6 | ((uint32_t)h7 << 16);
                *reinterpret_cast<uint4*>(dstbase + (qtr * 4 + c) * 128) = pk;
            }
        } else {
            uint4 z; z.x = z.y = z.z = z.w = 0u;
            #pragma unroll
            for (int c = 0; c < 4; ++c)
                *reinterpret_cast<uint4*>(dstbase + (qtr * 4 + c) * 128) = z;
        }
        a2p[r_][qtr] = ss;
        __syncthreads();
        if (t < TILE)
            rtl[t] = -0.5f * (a2p[t][0] + a2p[t][1] + a2p[t][2] + a2p[t][3]);
        // hoist A fragments: 8 ds_read_b128, once for the whole kernel
        const unsigned short* aLds = &ldsB[0][0] + (size_t)(wr * 2) * 2048 + lane * 8;
        #pragma unroll
        for (int i = 0; i < 2; ++i)
            #pragma unroll
            for (int kk = 0; kk < 4; ++kk)
                a[i * 4 + kk] = *reinterpret_cast<const short8*>(aLds + (size_t)i * 2048 + kk * 512);
        __syncthreads();   // all waves done reading A from ldsB before DMA overwrites
    } else {
        const int b2 = (int)blockIdx.x - nA;
        rowbase = b2 * TILE;
        const unsigned short* aG = Bp + (size_t)(b2 * 8 + wr * 2) * 2048 + lane * 8;
        #pragma unroll
        for (int i = 0; i < 2; ++i)
            #pragma unroll
            for (int kk = 0; kk < 4; ++kk)
                a[i * 4 + kk] = *reinterpret_cast<const short8*>(aG + (size_t)i * 2048 + kk * 512);
        const float inv_q2 = 0.5f / q;
        if (t < TILE)
            rtl[t] = -cw[rowbase + t].x * inv_q2;   // = -||c_row||^2/2 (up to 1 ulp)
        // rtl visible after the tile-0 __syncthreads below
    }

    float srow[2][4] = {};
    const float2* cwb = cw + wc * 32 + l15;
    const float* rtlp = &rtl[wr * 32 + quad * 4];   // i*16 applied at read

    // this wave stages its 2 KB eighth of each 16KB tile: 2 x 1KB DMA issues
    const int ldq = wid * 1024 + lane * 8;   // element offset (shorts)

    // DMA tile 0 into ldsB[0]
    {
        const unsigned short* g = Bp + ldq;
        unsigned short* l = &ldsB[0][0] + ldq;
        #pragma unroll
        for (int k = 0; k < 2; ++k)
            dma16(g + k * 512, l + k * 512);
    }
    __syncthreads();   // vmcnt drain: tile 0 resident (and rtl visible)

    for (int mt = 0; mt < nMt; ++mt) {
        if (mt + 1 < nMt) {
            // fire-and-forget DMA of tile mt+1 into the other buffer;
            // drained by the barrier at the END of this iteration.
            const unsigned short* g = Bp + (size_t)(mt + 1) * 8192 + ldq;
            unsigned short* l = &ldsB[(mt + 1) & 1][0] + ldq;
            #pragma unroll
            for (int k = 0; k < 2; ++k)
                dma16(g + k * 512, l + k * 512);
        }

        // column constants for this tile (L2-hot; latency covered by TLP)
        float2 cj[2];
        #pragma unroll
        for (int j = 0; j < 2; ++j) cj[j] = cwb[(size_t)mt * 64 + j * 16];

        // compute tile mt from LDS: 2 column groups of 16, K=128 each
        const unsigned short* bfr = &ldsB[mt & 1][0] + (size_t)(wc * 2) * 2048 + lane * 8;
        #pragma unroll
        for (int j = 0; j < 2; ++j) {
            short8 b[4];
            #pragma unroll
            for (int kk = 0; kk < 4; ++kk)
                b[kk] = *reinterpret_cast<const short8*>(bfr + (size_t)j * 2048 + kk * 512);

            // C-init = -||row||^2/2 from LDS (broadcast read, re-loaded per
            // iteration so the values don't occupy 8 regs across the loop)
            f32x4 acc4[2];
            acc4[0] = *reinterpret_cast<const f32x4*>(rtlp);
            acc4[1] = *reinterpret_cast<const f32x4*>(rtlp + 16);
            #pragma unroll
            for (int kk = 0; kk < 4; ++kk)
                #pragma unroll
                for (int i = 0; i < 2; ++i)
                    acc4[i] = __builtin_amdgcn_mfma_f32_16x16x32_bf16(
                        a[i * 4 + kk], b[kk], acc4[i], 0, 0, 0);

            // epilogue: u = q2*(dot - ||x||^2/2) - q*||c||^2 <= ~0
            #pragma unroll
            for (int i = 0; i < 2; ++i) {
                #pragma unroll
                for (int r = 0; r < 4; ++r) {
                    float u = fmaf(acc4[i][r], q2, -cj[j].x);
                    float e = __builtin_amdgcn_exp2f(u);
                    srow[i][r] = fmaf(e, cj[j].y, srow[i][r]);
                }
            }
        }

        __syncthreads();   // drains DMA(mt+1); all waves done reading buf[mt&1]
    }

    // reduce srow over the 16 lanes sharing a row
    #pragma unroll
    for (int i = 0; i < 2; ++i) {
        #pragma unroll
        for (int r = 0; r < 4; ++r) {
            int rl = wr * 32 + i * 16 + quad * 4 + r;
            float v = srow[i][r];
            v += __shfl_xor(v, 1);
            v += __shfl_xor(v, 2);
            v += __shfl_xor(v, 4);
            v += __shfl_xor(v, 8);
            if (l15 == 0)
                predbuf[rl][wc] = v;
        }
    }
    __syncthreads();

    float contrib = 0.f;
    if (t < TILE) {
        int grow = rowbase + t;
        if (!regmode) {
            if (grow < N) {
                float pred = predbuf[t][0] + predbuf[t][1];
                preds_out[grow] = pred;
                float d = pred - Yv[grow];
                contrib = d * d;
            }
        } else {
            float pred = predbuf[t][0] + predbuf[t][1];
            contrib = alpha[grow] * pred;
        }
    }
    contrib += __shfl_xor(contrib, 1);
    contrib += __shfl_xor(contrib, 2);
    contrib += __shfl_xor(contrib, 4);
    contrib += __shfl_xor(contrib, 8);
    contrib += __shfl_xor(contrib, 16);
    contrib += __shfl_xor(contrib, 32);
    if (lane == 0 && wid < 2) atomicAdd(regmode ? (acc + 1) : (acc + 0), contrib);

    __syncthreads();   // all waves' atomics drained before counting
    if (t == 0) {
        __threadfence();
        unsigned int old = atomicAdd((unsigned int*)(acc + 2), 1u);
        if (old == (unsigned int)(nBlk - 1)) {
            float lv = atomicAdd(acc + 0, 0.0f);   // coherent read-back
            float rv = atomicAdd(acc + 1, 0.0f);
            out0[0] = lv / (float)N + __expf(-penalty[0]) * rv;
        }
    }
}

extern "C" void kernel_launch(void* const* d_in, const int* in_sizes, int n_in,
                              void* d_out, int out_size, void* d_ws, size_t ws_size,
                              hipStream_t stream) {
    const float* X       = (const float*)d_in[0];
    const float* Y       = (const float*)d_in[1];
    const float* centers = (const float*)d_in[2];
    const float* alpha   = (const float*)d_in[3];
    const float* sigma   = (const float*)d_in[4];
    const float* penalty = (const float*)d_in[5];
    float* out = (float*)d_out;

    const int N = in_sizes[1];   // Y is [N,1]
    const int M = in_sizes[3];   // alpha is [M,1]

    unsigned short* Bp = (unsigned short*)d_ws;                 // M*128 bf16 = M*256 B
    float2* cw = (float2*)((char*)d_ws + (size_t)M * 256);      // M*8 B
    float* acc = (float*)((char*)d_ws + (size_t)M * 264);       // loss, reg, counter

    prep_kernel<<<M / 16, 256, 0, stream>>>(centers, alpha, sigma, Bp, cw, acc);

    const int nA  = (N + TILE - 1) / TILE;
    const int nMt = M / BCOLS;            // 64-col B tiles
    const int nBlk = nA + M / TILE;
    fused_kernel<<<nBlk, 512, 0, stream>>>(X, N, Y, Bp, cw, alpha, sigma, penalty,
                                           nA, nMt, nBlk, out + 1, out, acc);
}